// Round 1
// baseline (970.419 us; speedup 1.0000x reference)
//
#include <hip/hip_runtime.h>
#include <hip/hip_bf16.h>

typedef __attribute__((ext_vector_type(8))) short s16x8;
typedef __attribute__((ext_vector_type(4))) float f32x4;

#define MFMA(a, b, c) __builtin_amdgcn_mfma_f32_16x16x32_bf16((a), (b), (c), 0, 0, 0)

__device__ __forceinline__ short f2bf(float f) {
  unsigned u = __builtin_bit_cast(unsigned, f);
  u += 0x7FFFu + ((u >> 16) & 1u);
  return (short)(u >> 16);
}
__device__ __forceinline__ float bf2f(short s) {
  unsigned u = ((unsigned)(unsigned short)s) << 16;
  return __builtin_bit_cast(float, u);
}
__device__ __forceinline__ void async16(const void* g, void* l) {
  __builtin_amdgcn_global_load_lds((const __attribute__((address_space(1))) void*)g,
                                   (__attribute__((address_space(3))) void*)l, 16, 0, 0);
}

// ---------------- convert / transpose helpers ----------------

__global__ __launch_bounds__(256) void f32_to_bf16_k(const float* __restrict__ in,
                                                     short* __restrict__ out, int n4) {
  int i = blockIdx.x * 256 + threadIdx.x;
  if (i >= n4) return;
  float4 v = ((const float4*)in)[i];
  short4 o;
  o.x = f2bf(v.x); o.y = f2bf(v.y); o.z = f2bf(v.z); o.w = f2bf(v.w);
  ((short4*)out)[i] = o;
}

// out[n*K + k] = bf16(in[k*N + n]);  (B^T layout for GEMM)
__global__ __launch_bounds__(256) void transpose_bf16_k(const float* __restrict__ in,
                                                        short* __restrict__ out, int K, int N) {
  int idx = blockIdx.x * 256 + threadIdx.x;
  if (idx >= K * N) return;
  int n = idx / K;
  int k = idx - n * K;
  out[idx] = f2bf(in[k * N + n]);
}

// ---------------- GEMM core: 128x128 tile, BK=64, bf16 MFMA ----------------
// A: (M x 768) bf16 row-major.  Bt: (Nout x 768) bf16 row-major (B transposed).
// LDS chunks XOR-swizzled: stored chunk s holds global chunk ((s&7)^((s>>3)&7)) of row s>>3.

__device__ __forceinline__ void gemm_core(const short* __restrict__ A, const short* __restrict__ Bt,
                                          short* Asm, short* Bsm, int m0, int n0,
                                          f32x4 (&acc)[4][4]) {
  const int tid = threadIdx.x;
  const int lane = tid & 63;
  const int w = tid >> 6;
  const int wm = w >> 1, wn = w & 1;
  const int l15 = lane & 15, qd = lane >> 4;

  for (int kt = 0; kt < 12; ++kt) {
    __syncthreads();
#pragma unroll
    for (int i = 0; i < 4; ++i) {
      int s = i * 256 + tid;
      int row = s >> 3, cst = s & 7;
      int cg = cst ^ (row & 7);
      async16(A + (m0 + row) * 768 + kt * 64 + cg * 8, Asm + s * 8);
      async16(Bt + (n0 + row) * 768 + kt * 64 + cg * 8, Bsm + s * 8);
    }
    __builtin_amdgcn_s_waitcnt(0x0f70);  // vmcnt(0)
    __syncthreads();
#pragma unroll
    for (int ks = 0; ks < 2; ++ks) {
      s16x8 af[4], bfr[4];
#pragma unroll
      for (int mt = 0; mt < 4; ++mt) {
        int row = wm * 64 + mt * 16 + l15;
        int kc = ks * 4 + qd;
        af[mt] = *(const s16x8*)(Asm + row * 64 + ((kc ^ (row & 7)) << 3));
      }
#pragma unroll
      for (int nt = 0; nt < 4; ++nt) {
        int row = wn * 64 + nt * 16 + l15;
        int kc = ks * 4 + qd;
        bfr[nt] = *(const s16x8*)(Bsm + row * 64 + ((kc ^ (row & 7)) << 3));
      }
#pragma unroll
      for (int mt = 0; mt < 4; ++mt)
#pragma unroll
        for (int nt = 0; nt < 4; ++nt)
          acc[mt][nt] = MFMA(af[mt], bfr[nt], acc[mt][nt]);
    }
  }
}

// GEMM1: qkv = x_bf @ Wqkv + b.  Scatter epilogue to q/k/v (B,H,197,64) bf16.
__global__ __launch_bounds__(256) void gemm_qkv(const short* __restrict__ A, const short* __restrict__ Bt,
                                                const float* __restrict__ bias,
                                                short* __restrict__ qo, short* __restrict__ ko,
                                                short* __restrict__ vo) {
  __shared__ short Asm[128 * 64];
  __shared__ short Bsm[128 * 64];
  const int m0 = blockIdx.x * 128;
  const int n0 = blockIdx.y * 128;
  const f32x4 z4 = {0.f, 0.f, 0.f, 0.f};
  f32x4 acc[4][4];
#pragma unroll
  for (int i = 0; i < 4; ++i)
#pragma unroll
    for (int j = 0; j < 4; ++j) acc[i][j] = z4;
  gemm_core(A, Bt, Asm, Bsm, m0, n0, acc);

  const int tid = threadIdx.x, lane = tid & 63, w = tid >> 6;
  const int wm = w >> 1, wn = w & 1, l15 = lane & 15, qd = lane >> 4;

  float bv[4];
  short* dstp[4];
  int coff[4];  // (h*197*... ) partial: offset contribution of (h, d)
#pragma unroll
  for (int nt = 0; nt < 4; ++nt) {
    int n = n0 + wn * 64 + nt * 16 + l15;
    bv[nt] = bias[n];
    int s = n / 768;
    int rem = n - s * 768;
    int hh = rem >> 6, d = rem & 63;
    dstp[nt] = (s == 0) ? qo : ((s == 1) ? ko : vo);
    coff[nt] = hh * 197 * 64 + d;
  }
#pragma unroll
  for (int mt = 0; mt < 4; ++mt) {
#pragma unroll
    for (int r = 0; r < 4; ++r) {
      int m = m0 + wm * 64 + mt * 16 + qd * 4 + r;
      int bb = m / 197;
      int tok = m - bb * 197;
      size_t base = (size_t)bb * (12 * 197 * 64) + (size_t)tok * 64;
#pragma unroll
      for (int nt = 0; nt < 4; ++nt)
        dstp[nt][base + coff[nt]] = f2bf(acc[mt][nt][r] + bv[nt]);
    }
  }
}

// GEMM2: out = aout_bf @ Wproj + b, fp32 row-major output.
__global__ __launch_bounds__(256) void gemm_proj(const short* __restrict__ A, const short* __restrict__ Bt,
                                                 const float* __restrict__ bias,
                                                 float* __restrict__ out) {
  __shared__ short Asm[128 * 64];
  __shared__ short Bsm[128 * 64];
  const int m0 = blockIdx.x * 128;
  const int n0 = blockIdx.y * 128;
  const f32x4 z4 = {0.f, 0.f, 0.f, 0.f};
  f32x4 acc[4][4];
#pragma unroll
  for (int i = 0; i < 4; ++i)
#pragma unroll
    for (int j = 0; j < 4; ++j) acc[i][j] = z4;
  gemm_core(A, Bt, Asm, Bsm, m0, n0, acc);

  const int tid = threadIdx.x, lane = tid & 63, w = tid >> 6;
  const int wm = w >> 1, wn = w & 1, l15 = lane & 15, qd = lane >> 4;
#pragma unroll
  for (int mt = 0; mt < 4; ++mt) {
#pragma unroll
    for (int r = 0; r < 4; ++r) {
      int m = m0 + wm * 64 + mt * 16 + qd * 4 + r;
      float* orow = out + (size_t)m * 768;
#pragma unroll
      for (int nt = 0; nt < 4; ++nt) {
        int n = n0 + wn * 64 + nt * 16 + l15;
        orow[n] = acc[mt][nt][r] + bias[n];
      }
    }
  }
}

// ---------------- fused attention + depthwise conv ----------------
// 1 WG = (b,h). K in LDS [197][64] swizzled; V^T in LDS [64][256] swizzled (keys 197..223 zeroed);
// per-wave P chunk [16][40] for C-layout -> A-layout transpose.
__global__ __launch_bounds__(256) void attn_fused(const short* __restrict__ qa, const short* __restrict__ ka,
                                                  const short* __restrict__ va,
                                                  const float* __restrict__ dwcw,
                                                  const float* __restrict__ dwcb,
                                                  short* __restrict__ aout) {
  __shared__ short Klds[197 * 64];
  __shared__ short Vt[64 * 256];
  __shared__ short Plds[4][16 * 40];
  __shared__ float Wc[576];

  const int tid = threadIdx.x;
  const int lane = tid & 63;
  const int w = tid >> 6;
  const int l15 = lane & 15, qd = lane >> 4;
  const int bh = blockIdx.x;
  const int b = bh / 12;
  const int h = bh - b * 12;
  const short* kb = ka + (size_t)bh * (197 * 64);
  const short* vb = va + (size_t)bh * (197 * 64);
  const short* qb = qa + (size_t)bh * (197 * 64);

  // stage K (swizzled chunks)
  for (int c = tid; c < 197 * 8; c += 256) {
    int row = c >> 3, cc = c & 7;
    s16x8 v8 = *(const s16x8*)(kb + row * 64 + cc * 8);
    *(s16x8*)(Klds + row * 64 + ((cc ^ (row & 7)) << 3)) = v8;
  }
  // stage V transposed (Vt[d][key], swizzled along key-chunks)
  for (int c = tid; c < 197 * 8; c += 256) {
    int key = c >> 3, cc = c & 7;
    s16x8 v8 = *(const s16x8*)(vb + key * 64 + cc * 8);
    int kc = key >> 3, km = key & 7;
#pragma unroll
    for (int j = 0; j < 8; ++j) {
      int d = cc * 8 + j;
      Vt[d * 256 + ((kc ^ (d & 7)) << 3) + km] = v8[j];
    }
  }
  // zero Vt pad keys 197..223
  for (int i = tid; i < 64 * 27; i += 256) {
    int d = i / 27;
    int key = 197 + (i - d * 27);
    Vt[d * 256 + (((key >> 3) ^ (d & 7)) << 3) + (key & 7)] = 0;
  }
  // depthwise conv weights for this head's 64 channels
  for (int i = tid; i < 576; i += 256) Wc[i] = dwcw[h * 576 + i];
  __syncthreads();

  float cbv[4];
#pragma unroll
  for (int nt = 0; nt < 4; ++nt) cbv[nt] = dwcb[h * 64 + nt * 16 + l15];

  for (int qt = w; qt < 13; qt += 4) {
    const int m0 = qt * 16;
    int mrow = m0 + l15; if (mrow > 196) mrow = 196;
    s16x8 qf0 = *(const s16x8*)(qb + mrow * 64 + qd * 8);
    s16x8 qf1 = *(const s16x8*)(qb + mrow * 64 + 32 + qd * 8);

    // S = Q K^T  (13 key tiles of 16)
    f32x4 S[13];
#pragma unroll
    for (int kt = 0; kt < 13; ++kt) {
      int krow = kt * 16 + l15; if (krow > 196) krow = 196;
      s16x8 kf0 = *(const s16x8*)(Klds + krow * 64 + ((qd ^ (krow & 7)) << 3));
      s16x8 kf1 = *(const s16x8*)(Klds + krow * 64 + (((4 + qd) ^ (krow & 7)) << 3));
      f32x4 sa = {0.f, 0.f, 0.f, 0.f};
      sa = MFMA(qf0, kf0, sa);
      sa = MFMA(qf1, kf1, sa);
      S[kt] = sa;
    }
    // scale + mask invalid keys (cols 197..207 live in tile 12 at l15>4)
    const bool maskme = (l15 > 4);
#pragma unroll
    for (int kt = 0; kt < 13; ++kt) {
#pragma unroll
      for (int r = 0; r < 4; ++r) {
        float sv = S[kt][r] * 0.125f;
        if (kt == 12 && maskme) sv = -1e30f;
        S[kt][r] = sv;
      }
    }
    // softmax over 197 keys: row r lives in the 16 lanes sharing qd
    float li[4];
#pragma unroll
    for (int r = 0; r < 4; ++r) {
      float m = S[0][r];
#pragma unroll
      for (int kt = 1; kt < 13; ++kt) m = fmaxf(m, S[kt][r]);
#pragma unroll
      for (int off = 1; off < 16; off <<= 1) m = fmaxf(m, __shfl_xor(m, off));
      float l = 0.f;
#pragma unroll
      for (int kt = 0; kt < 13; ++kt) {
        float p = __builtin_amdgcn_exp2f((S[kt][r] - m) * 1.44269504f);
        S[kt][r] = p;
        l += p;
      }
#pragma unroll
      for (int off = 1; off < 16; off <<= 1) l += __shfl_xor(l, off);
      li[r] = l;
    }

    // O = P V   (P: C-layout -> LDS -> A-layout, 7 chunks of K=32)
    const f32x4 z4 = {0.f, 0.f, 0.f, 0.f};
    f32x4 O[4] = {z4, z4, z4, z4};
    short* Pw = &Plds[w][0];
#pragma unroll
    for (int kt2 = 0; kt2 < 7; ++kt2) {
#pragma unroll
      for (int sub = 0; sub < 2; ++sub) {
        const int ktile = kt2 * 2 + sub;
#pragma unroll
        for (int r = 0; r < 4; ++r) {
          short pv = 0;
          if (ktile < 13) pv = f2bf(S[ktile][r]);
          Pw[(qd * 4 + r) * 40 + sub * 16 + l15] = pv;
        }
      }
      __builtin_amdgcn_s_waitcnt(0xc07f);  // lgkmcnt(0)
      s16x8 pf = *(const s16x8*)(Pw + l15 * 40 + qd * 8);
#pragma unroll
      for (int nt = 0; nt < 4; ++nt) {
        int d = nt * 16 + l15;
        s16x8 vf = *(const s16x8*)(Vt + d * 256 + (((kt2 * 4 + qd) ^ (d & 7)) << 3));
        O[nt] = MFMA(pf, vf, O[nt]);
      }
    }

    // epilogue: 1/l, depthwise conv from Vt, store bf16 (B,N,C)
#pragma unroll
    for (int r = 0; r < 4; ++r) {
      int tok = m0 + qd * 4 + r;
      if (tok > 196) continue;
      float linv = __builtin_amdgcn_rcpf(li[r]);
      int py = 0, px = 0;
      const bool dconv = (tok >= 1);
      if (dconv) { int p = tok - 1; py = p / 14; px = p - py * 14; }
      size_t ob = ((size_t)b * 197 + tok) * 768 + h * 64;
#pragma unroll
      for (int nt = 0; nt < 4; ++nt) {
        int d = nt * 16 + l15;
        float val = O[nt][r] * linv;
        if (dconv) {
          float cv = cbv[nt];
#pragma unroll
          for (int dy = -1; dy <= 1; ++dy) {
            int yy = py + dy;
#pragma unroll
            for (int dx = -1; dx <= 1; ++dx) {
              int xx = px + dx;
              if (yy >= 0 && yy < 14 && xx >= 0 && xx < 14) {
                int key = 1 + yy * 14 + xx;
                float vv = bf2f(Vt[d * 256 + (((key >> 3) ^ (d & 7)) << 3) + (key & 7)]);
                cv += Wc[d * 9 + (dy + 1) * 3 + (dx + 1)] * vv;
              }
            }
          }
          val += cv;
        }
        aout[ob + d] = f2bf(val);
      }
    }
  }
}

// ---------------- launch ----------------

extern "C" void kernel_launch(void* const* d_in, const int* in_sizes, int n_in,
                              void* d_out, int out_size, void* d_ws, size_t ws_size,
                              hipStream_t stream) {
  const float* x     = (const float*)d_in[0];
  const float* Wqkv  = (const float*)d_in[1];
  const float* bqkv  = (const float*)d_in[2];
  const float* Wproj = (const float*)d_in[3];
  const float* bproj = (const float*)d_in[4];
  const float* dwcw  = (const float*)d_in[5];
  const float* dwcb  = (const float*)d_in[6];
  float* out = (float*)d_out;

  const size_t XE = (size_t)50432 * 768;  // 38,731,776 elems
  short* ws     = (short*)d_ws;
  short* xbf    = ws;
  short* wqkvT  = xbf + XE;
  short* wprojT = wqkvT + (size_t)2304 * 768;
  short* qarr   = wprojT + (size_t)768 * 768;
  short* karr   = qarr + XE;
  short* varr   = karr + XE;
  short* aoutb  = xbf;  // reuse x_bf space (dead after gemm_qkv)

  f32_to_bf16_k<<<(int)((XE / 4 + 255) / 256), 256, 0, stream>>>(x, xbf, (int)(XE / 4));
  transpose_bf16_k<<<(2304 * 768 + 255) / 256, 256, 0, stream>>>(Wqkv, wqkvT, 768, 2304);
  transpose_bf16_k<<<(768 * 768 + 255) / 256, 256, 0, stream>>>(Wproj, wprojT, 768, 768);
  gemm_qkv<<<dim3(394, 18), 256, 0, stream>>>(xbf, wqkvT, bqkv, qarr, karr, varr);
  attn_fused<<<3072, 256, 0, stream>>>(qarr, karr, varr, dwcw, dwcb, aoutb);
  gemm_proj<<<dim3(394, 6), 256, 0, stream>>>(aoutb, wprojT, bproj, out);
}